// Round 5
// baseline (146.222 us; speedup 1.0000x reference)
//
#include <hip/hip_runtime.h>

// EmotionCaps dynamic routing (fp32 I/O):
// u: [B=64, N=1024, I=64] f32; W: [N=1024, E=8, O=32, I=64] f32
// out: v [B=64, E=8, O=32] f32
// Stage 1: u_hat (bf16, 32MB ws) = per-n GEMM via bf16 MFMA.
//          B-fragments streamed directly from global (no W LDS stage);
//          u staged in LDS for A-frags; coalesced LDS-transpose epilogue.
// Stage 2: 3 routing passes (identity: b1 = uh.v0, b2 = uh.(v0+v1) — no
//          logit storage), route inner loop phase-split for 8-way ILP.

#define B_  64
#define N_  1024
#define I_  64
#define E_  8
#define O_  32
#define EO_ 256
#define PAD_ 72    // padded LDS row (bf16 elems): 144B stride

typedef __bf16 bf16x8 __attribute__((ext_vector_type(8)));
typedef __bf16 bf16x4v __attribute__((ext_vector_type(4)));
typedef float  f32x4  __attribute__((ext_vector_type(4)));

__device__ __forceinline__ float bf2f(unsigned int h) {
    unsigned int x = (h & 0xffffu) << 16;
    return __builtin_bit_cast(float, x);
}
__device__ __forceinline__ unsigned short f2bf(float f) {
    unsigned int x = __builtin_bit_cast(unsigned int, f);
    unsigned int r = x + 0x7fffu + ((x >> 16) & 1u);   // RNE
    return (unsigned short)(r >> 16);
}
__device__ __forceinline__ void cvt_store4(unsigned short* dst, float4 q) {
    bf16x4v v;
    v[0] = (__bf16)q.x; v[1] = (__bf16)q.y; v[2] = (__bf16)q.z; v[3] = (__bf16)q.w;
    *(bf16x4v*)dst = v;
}
__device__ __forceinline__ bf16x8 cvt8(const float* __restrict__ p) {
    float4 q0 = *(const float4*)p;
    float4 q1 = *(const float4*)(p + 4);
    bf16x8 a;
    a[0] = (__bf16)q0.x; a[1] = (__bf16)q0.y; a[2] = (__bf16)q0.z; a[3] = (__bf16)q0.w;
    a[4] = (__bf16)q1.x; a[5] = (__bf16)q1.y; a[6] = (__bf16)q1.z; a[7] = (__bf16)q1.w;
    return a;
}

// ---------------------------------------------------------------------------
// K1: one block per n. D[64b x 256eo] = u[:,n,:] . W[n]^T via 16x16x32 bf16
// MFMA (fragment layouts verified rounds 3/4). u staged in LDS (A-frags);
// W fragments streamed from global (each eo-row of W[n] is 256B contiguous,
// fully consumed by the wave). Epilogue transposes D through LDS for
// 512B-contiguous uint2 stores. LDS: ul 9216 + Dtile 33792 = 43008 B.
// ---------------------------------------------------------------------------
__global__ __launch_bounds__(256) void k_uhat(const float* __restrict__ u,
                                              const float* __restrict__ W,
                                              unsigned short* __restrict__ uh) {
    const int n = blockIdx.x;
    const int t = threadIdx.x;
    const int w = t >> 6, l = t & 63;
    const int m16 = l & 15, g = l >> 4;

    __shared__ __align__(16) unsigned short ul[B_ * PAD_];      //  9216 B
    __shared__ __align__(16) unsigned short Dt[B_ * 264];       // 33792 B

    // stage u[:, n, :]: 1024 float4, coalesced, fp32->bf16
#pragma unroll
    for (int j = 0; j < 4; ++j) {
        int idx = j * 256 + t;
        int b = idx >> 4, c = idx & 15;
        float4 q = *(const float4*)(u + (size_t)b * (N_ * I_) + n * I_ + c * 4);
        cvt_store4(&ul[b * PAD_ + c * 4], q);
    }
    __syncthreads();

    // A fragments: A[m=lane&15][k=(lane>>4)*8+j]
    bf16x8 afr[4][2];
#pragma unroll
    for (int mt = 0; mt < 4; ++mt)
#pragma unroll
        for (int ks = 0; ks < 2; ++ks)
            afr[mt][ks] = *(const bf16x8*)&ul[(mt * 16 + m16) * PAD_ + ks * 32 + g * 8];

    f32x4 acc[4][4];
#pragma unroll
    for (int nt = 0; nt < 4; ++nt)
#pragma unroll
        for (int mt = 0; mt < 4; ++mt)
            acc[nt][mt] = (f32x4){0.f, 0.f, 0.f, 0.f};

    const float* Wn = W + (size_t)n * (EO_ * I_);
#pragma unroll
    for (int nt = 0; nt < 4; ++nt) {
        const int eo = w * 64 + nt * 16 + m16;
        const float* wp = Wn + (size_t)eo * I_ + g * 8;
        bf16x8 b0 = cvt8(wp);           // k = g*8..g*8+7
        bf16x8 b1 = cvt8(wp + 32);      // k = 32+g*8..
#pragma unroll
        for (int mt = 0; mt < 4; ++mt) {
            acc[nt][mt] = __builtin_amdgcn_mfma_f32_16x16x32_bf16(afr[mt][0], b0, acc[nt][mt], 0, 0, 0);
            acc[nt][mt] = __builtin_amdgcn_mfma_f32_16x16x32_bf16(afr[mt][1], b1, acc[nt][mt], 0, 0, 0);
        }
    }

    // epilogue: D lane map col=lane&15, row=(lane>>4)*4+reg -> LDS transpose
#pragma unroll
    for (int nt = 0; nt < 4; ++nt) {
        const int col = w * 64 + nt * 16 + m16;
#pragma unroll
        for (int mt = 0; mt < 4; ++mt)
#pragma unroll
            for (int r = 0; r < 4; ++r)
                Dt[(mt * 16 + g * 4 + r) * 264 + col] = f2bf(acc[nt][mt][r]);
    }
    __syncthreads();
    // store: 64 rows of 512B contiguous (uint2 per lane)
#pragma unroll
    for (int r = 0; r < 16; ++r) {
        const int row = r * 4 + w;
        uint2 q = *(const uint2*)&Dt[row * 264 + l * 4];
        *(uint2*)(uh + (size_t)row * (N_ * EO_) + (size_t)n * EO_ + l * 4) = q;
    }
}

// ---------------------------------------------------------------------------
// K2: one routing pass, phase-split for ILP. Block = (b, chunk of 32 n);
// wave handles 8 n. Lane l owns eo = 4l..4l+3 (e = l>>3).
//  Phase A: 8 independent load+dot4+shfl(1,2,4) chains  -> logits
//  Phase B: 8 interleaved softmax trees shfl(8,16,32)   -> c[8]
//  Phase C: 8x4 register FMA accumulate
// mode 0: c = 1/8 (skip A/B). Output: race-free partials sp[blk][eo].
// ---------------------------------------------------------------------------
__global__ __launch_bounds__(256) void k_route(const unsigned short* __restrict__ uh,
                                               const float* __restrict__ vin,
                                               float* __restrict__ sp,
                                               int mode) {
    const int blk = blockIdx.x;
    const int b = blk >> 5, chunk = blk & 31;
    const int t = threadIdx.x, wave = t >> 6, l = t & 63;

    const unsigned short* base = uh + (size_t)b * (N_ * EO_)
                                    + (size_t)(chunk * 32 + wave * 8) * EO_ + 4 * l;
    float x[8][4];
    float c[8];

    if (mode == 0) {
#pragma unroll
        for (int nn = 0; nn < 8; ++nn) {
            uint2 p = *(const uint2*)(base + nn * EO_);
            x[nn][0] = bf2f(p.x); x[nn][1] = bf2f(p.x >> 16);
            x[nn][2] = bf2f(p.y); x[nn][3] = bf2f(p.y >> 16);
            c[nn] = 0.125f;
        }
    } else {
        float4 v4 = *(const float4*)(vin + b * EO_ + 4 * l);
        float lg[8];
#pragma unroll
        for (int nn = 0; nn < 8; ++nn) {          // phase A: independent chains
            uint2 p = *(const uint2*)(base + nn * EO_);
            x[nn][0] = bf2f(p.x); x[nn][1] = bf2f(p.x >> 16);
            x[nn][2] = bf2f(p.y); x[nn][3] = bf2f(p.y >> 16);
            float pd = x[nn][0] * v4.x + x[nn][1] * v4.y
                     + x[nn][2] * v4.z + x[nn][3] * v4.w;
            pd += __shfl_xor(pd, 1);
            pd += __shfl_xor(pd, 2);
            pd += __shfl_xor(pd, 4);              // logit(n, e) in all 8 e-lanes
            lg[nn] = pd;
        }
        // phase B: softmax over E (masks 8,16,32), 8 n interleaved
        float mx[8];
#pragma unroll
        for (int nn = 0; nn < 8; ++nn) mx[nn] = lg[nn];
#pragma unroll
        for (int nn = 0; nn < 8; ++nn) mx[nn] = fmaxf(mx[nn], __shfl_xor(mx[nn], 8));
#pragma unroll
        for (int nn = 0; nn < 8; ++nn) mx[nn] = fmaxf(mx[nn], __shfl_xor(mx[nn], 16));
#pragma unroll
        for (int nn = 0; nn < 8; ++nn) mx[nn] = fmaxf(mx[nn], __shfl_xor(mx[nn], 32));
        float ex[8], sm[8];
#pragma unroll
        for (int nn = 0; nn < 8; ++nn) { ex[nn] = __expf(lg[nn] - mx[nn]); sm[nn] = ex[nn]; }
#pragma unroll
        for (int nn = 0; nn < 8; ++nn) sm[nn] += __shfl_xor(sm[nn], 8);
#pragma unroll
        for (int nn = 0; nn < 8; ++nn) sm[nn] += __shfl_xor(sm[nn], 16);
#pragma unroll
        for (int nn = 0; nn < 8; ++nn) sm[nn] += __shfl_xor(sm[nn], 32);
#pragma unroll
        for (int nn = 0; nn < 8; ++nn) c[nn] = ex[nn] * __builtin_amdgcn_rcpf(sm[nn]);
    }

    // phase C: accumulate
    float a0 = 0.f, a1 = 0.f, a2 = 0.f, a3 = 0.f;
#pragma unroll
    for (int nn = 0; nn < 8; ++nn) {
        a0 = fmaf(c[nn], x[nn][0], a0); a1 = fmaf(c[nn], x[nn][1], a1);
        a2 = fmaf(c[nn], x[nn][2], a2); a3 = fmaf(c[nn], x[nn][3], a3);
    }

    __shared__ __align__(16) float red[4][EO_];
    *(float4*)&red[wave][4 * l] = make_float4(a0, a1, a2, a3);
    __syncthreads();
    sp[(size_t)blk * EO_ + t] = red[0][t] + red[1][t] + red[2][t] + red[3][t];
}

// ---------------------------------------------------------------------------
// K3: reduce partials (32 per (b,eo)), squash over o, maintain vwork:
// it0 -> vsum=v0, vwork=v0 ; it1 -> vwork=v0+v1 ; it2 -> out.
// ---------------------------------------------------------------------------
__global__ __launch_bounds__(256) void k_squash(const float* __restrict__ sp,
                                                float* __restrict__ vsum,
                                                float* __restrict__ vwork,
                                                float* __restrict__ out,
                                                int it) {
    const int b = blockIdx.x, t = threadIdx.x;   // t = eo
    float sv = 0.f;
#pragma unroll
    for (int ci = 0; ci < 32; ++ci) sv += sp[(size_t)(b * 32 + ci) * EO_ + t];
    float sq = sv * sv;
    sq += __shfl_xor(sq, 1);
    sq += __shfl_xor(sq, 2);
    sq += __shfl_xor(sq, 4);
    sq += __shfl_xor(sq, 8);
    sq += __shfl_xor(sq, 16);                    // |s|^2 over o (32-lane group)
    float nrm = sqrtf(sq);
    float vv = sq / ((1.f + sq) * (nrm + 1e-8f)) * sv;
    if (it == 0)      { vsum[b * EO_ + t] = vv; vwork[b * EO_ + t] = vv; }
    else if (it == 1) { vwork[b * EO_ + t] = vsum[b * EO_ + t] + vv; }
    else              { out[b * EO_ + t] = vv; }
}

extern "C" void kernel_launch(void* const* d_in, const int* in_sizes, int n_in,
                              void* d_out, int out_size, void* d_ws, size_t ws_size,
                              hipStream_t stream) {
    const float* u = (const float*)d_in[0];     // f32 [64,1024,64]
    const float* W = (const float*)d_in[1];     // f32 [1024,8,32,64]
    float* out = (float*)d_out;                 // f32 [64,8,32]

    char* ws = (char*)d_ws;
    unsigned short* uh = (unsigned short*)ws;        // 33,554,432 B  u_hat bf16
    float* sp    = (float*)(ws + 33554432);          //  2,097,152 B  partials
    float* vsum  = (float*)(ws + 35651584);          //     65,536 B
    float* vwork = (float*)(ws + 35717120);          //     65,536 B

    k_uhat  <<<dim3(N_),   dim3(256), 0, stream>>>(u, W, uh);
    k_route <<<dim3(2048), dim3(256), 0, stream>>>(uh, vwork, sp, 0);
    k_squash<<<dim3(B_),   dim3(256), 0, stream>>>(sp, vsum, vwork, out, 0);
    k_route <<<dim3(2048), dim3(256), 0, stream>>>(uh, vwork, sp, 1);
    k_squash<<<dim3(B_),   dim3(256), 0, stream>>>(sp, vsum, vwork, out, 1);
    k_route <<<dim3(2048), dim3(256), 0, stream>>>(uh, vwork, sp, 1);
    k_squash<<<dim3(B_),   dim3(256), 0, stream>>>(sp, vsum, vwork, out, 2);
}